// Round 1
// baseline (318.334 us; speedup 1.0000x reference)
//
#include <hip/hip_runtime.h>

typedef float f32x4 __attribute__((ext_vector_type(4)));

// Tiny pre-kernel: filter sums -> ws[0..3] = {sum(gl), sum(gh), sum(fl), sum(fh)}
__global__ void qwt_sums_kernel(const float* __restrict__ gl, const float* __restrict__ gh,
                                const float* __restrict__ fl, const float* __restrict__ fh,
                                float* __restrict__ ws) {
    int t = threadIdx.x;
    if (t < 4) {
        const float* p = (t == 0) ? gl : (t == 1) ? gh : (t == 2) ? fl : fh;
        float s = 0.f;
        #pragma unroll
        for (int i = 0; i < 16; i++) s += p[i];
        ws[t] = s;
    }
}

// One wave (64 lanes) == one output row (256 px, 4 px/lane).
// grid: 4096 blocks x 256 threads = 16384 waves = 4*16*256 rows.
__global__ __launch_bounds__(256) void qwt_main_kernel(const float* __restrict__ img,
                                                       const float* __restrict__ ws,
                                                       float* __restrict__ out) {
    const float w0 = -0.09375f, w1 = 0.59375f;  // CUBIC_W = {w0, w1, w1, w0}

    int t    = blockIdx.x * 256 + threadIdx.x;
    int lane = t & 63;
    int row  = t >> 6;        // 0..16383 flat (b,c,y)
    int y    = row & 255;
    int bc   = row >> 8;      // 0..63 = b*16 + c
    int x0   = lane << 2;     // 4 output px per lane

    // load scales early (uniform, L1-broadcast)
    float sg = ws[0], sh = ws[1], sfl = ws[2], sfh = ws[3];

    const float* src = img + (size_t)bc * (512 * 512);

    float acc0 = 0.f, acc1 = 0.f, acc2 = 0.f, acc3 = 0.f;
    #pragma unroll
    for (int j = 0; j < 4; j++) {
        int ry = 2 * y - 1 + j;               // wave-uniform
        ry = ry < 0 ? 0 : (ry > 511 ? 511 : ry);
        const f32x4* rp4 = (const f32x4*)(src + (size_t)ry * 512);
        // lane covers source cols 8*lane .. 8*lane+7, 16B-aligned
        f32x4 v0 = rp4[2 * lane];
        f32x4 v1 = rp4[2 * lane + 1];
        // halo columns via cross-lane shuffle; border clamp at lane 0 / 63
        float left  = __shfl_up(v1.w, 1);     // col 8*lane - 1
        float right = __shfl_down(v0.x, 1);   // col 8*lane + 8
        if (lane == 0)  left  = v0.x;         // clamp col -1 -> 0
        if (lane == 63) right = v1.w;         // clamp col 512 -> 511

        float h0 = w0 * left + w1 * v0.x + w1 * v0.y + w0 * v0.z;
        float h1 = w0 * v0.y + w1 * v0.z + w1 * v0.w + w0 * v1.x;
        float h2 = w0 * v0.w + w1 * v1.x + w1 * v1.y + w0 * v1.z;
        float h3 = w0 * v1.y + w1 * v1.z + w1 * v1.w + w0 * right;

        float wj = (j == 0 || j == 3) ? w0 : w1;
        acc0 += wj * h0; acc1 += wj * h1; acc2 += wj * h2; acc3 += wj * h3;
    }

    int b   = bc >> 4;          // batch 0..3
    int cc_ = bc & 15;          // channel 0..15
    size_t rowoff = ((size_t)y << 8) + (size_t)x0;   // y*256 + x0
    const size_t P  = 65536;                         // 256*256
    const size_t HB = 16777216;                      // LL element count

    // Incremental base pointers: chan = b*64 + q*16 + cc_, so per-q step is
    // 16*P for LL and 48*P for H.
    float* llp = out + ((size_t)(b * 64 + cc_)) * P + rowoff;
    float* hp  = out + HB + ((size_t)(b * 64 + cc_)) * 3 * P + rowoff;

    #pragma unroll
    for (int q = 0; q < 4; q++) {
        float f1g = (q & 1) ? sfl : sg;
        float f1h = (q & 1) ? sfh : sh;
        float f2g = (q & 2) ? sfl : sg;
        float f2h = (q & 2) ? sfh : sh;

        // LL: scale f1g*f2g
        {
            float s = f1g * f2g;
            f32x4 v = {acc0 * s, acc1 * s, acc2 * s, acc3 * s};
            __builtin_nontemporal_store(v, (f32x4*)llp);
        }
        // H: r=0 (f1g*f2h), r=1 (f1h*f2g), r=2 (f1h*f2h)
        {
            float s = f1g * f2h;
            f32x4 v = {acc0 * s, acc1 * s, acc2 * s, acc3 * s};
            __builtin_nontemporal_store(v, (f32x4*)hp);
        }
        {
            float s = f1h * f2g;
            f32x4 v = {acc0 * s, acc1 * s, acc2 * s, acc3 * s};
            __builtin_nontemporal_store(v, (f32x4*)(hp + P));
        }
        {
            float s = f1h * f2h;
            f32x4 v = {acc0 * s, acc1 * s, acc2 * s, acc3 * s};
            __builtin_nontemporal_store(v, (f32x4*)(hp + 2 * P));
        }

        llp += 16 * P;
        hp  += 48 * P;
    }
}

extern "C" void kernel_launch(void* const* d_in, const int* in_sizes, int n_in,
                              void* d_out, int out_size, void* d_ws, size_t ws_size,
                              hipStream_t stream) {
    const float* img = (const float*)d_in[0];
    const float* gl  = (const float*)d_in[1];
    const float* gh  = (const float*)d_in[2];
    const float* fl  = (const float*)d_in[3];
    const float* fh  = (const float*)d_in[4];
    float* out = (float*)d_out;
    float* ws  = (float*)d_ws;

    qwt_sums_kernel<<<1, 64, 0, stream>>>(gl, gh, fl, fh, ws);
    // 4*16*256 rows, one wave per row, 4 waves per block
    qwt_main_kernel<<<4096, 256, 0, stream>>>(img, ws, out);
}